// Round 1
// baseline (392.008 us; speedup 1.0000x reference)
//
#include <hip/hip_runtime.h>
#include <hip/hip_bf16.h>

typedef __attribute__((ext_vector_type(4))) float f32x4;
typedef __attribute__((ext_vector_type(8))) short short8;
typedef __attribute__((ext_vector_type(4))) short short4v;
using bf16 = __hip_bfloat16;

__device__ __forceinline__ short f2bf(float x) {
  union { bf16 h; short s; } u;
  u.h = __float2bfloat16(x);
  return u.s;
}

__device__ __forceinline__ void gload16(const void* g, void* l) {
  __builtin_amdgcn_global_load_lds(
      (const __attribute__((address_space(1))) void*)g,
      (__attribute__((address_space(3))) void*)l, 16, 0, 0);
}

// ---------------- fp32 -> bf16 conversion (weights) ----------------
__global__ void cvt_f32_to_bf16(const float* __restrict__ src,
                                bf16* __restrict__ dst, int n4) {
  int i = blockIdx.x * blockDim.x + threadIdx.x;
  if (i >= n4) return;
  f32x4 v = ((const f32x4*)src)[i];
  short4v o;
  o[0] = f2bf(v[0]); o[1] = f2bf(v[1]); o[2] = f2bf(v[2]); o[3] = f2bf(v[3]);
  ((short4v*)dst)[i] = o;
}

// ---------------- GEMM: C[M][N] = A[M][K] * B[N][K]^T + bias ----------------
// 128x128 tile, BK=64, 256 threads (4 waves, 2x2), mfma_f32_16x16x32_bf16.
// Operands swapped in the MFMA so lane holds 4 consecutive N-columns -> packed stores.
template<bool A_F32, bool OUT_BF16>
__global__ __launch_bounds__(256) void gemm_bt(
    const void* __restrict__ Av, int lda,
    const bf16* __restrict__ B, int ldb,
    const float* __restrict__ bias,
    void* __restrict__ Cv, int ldc, int K)
{
  __shared__ __align__(16) bf16 lA[128 * 64];
  __shared__ __align__(16) bf16 lB[128 * 64];
  const int tid  = threadIdx.x;
  const int wave = tid >> 6;
  const int lane = tid & 63;
  const int bm = blockIdx.y * 128;
  const int bn = blockIdx.x * 128;
  const int wm = (wave >> 1) * 64;
  const int wn = (wave & 1) * 64;
  const int l15 = lane & 15;
  const int kg  = lane >> 4;

  f32x4 acc[4][4];
#pragma unroll
  for (int i = 0; i < 4; ++i)
#pragma unroll
    for (int j = 0; j < 4; ++j)
      acc[i][j] = (f32x4)0.f;

  const int srow = lane >> 3;        // 0..7
  const int scol = (lane & 7) * 8;   // element col (8 elems / lane)

  for (int kt = 0; kt < K; kt += 64) {
    __syncthreads();
#pragma unroll
    for (int it = 0; it < 4; ++it) {
      const int seg = it * 4 + wave;     // 0..15
      const int row = seg * 8 + srow;    // 0..127
      if constexpr (A_F32) {
        const float* ga = (const float*)Av + (size_t)(bm + row) * lda + kt + scol;
        f32x4 v0 = *(const f32x4*)ga;
        f32x4 v1 = *(const f32x4*)(ga + 4);
        short8 p;
        p[0] = f2bf(v0[0]); p[1] = f2bf(v0[1]); p[2] = f2bf(v0[2]); p[3] = f2bf(v0[3]);
        p[4] = f2bf(v1[0]); p[5] = f2bf(v1[1]); p[6] = f2bf(v1[2]); p[7] = f2bf(v1[3]);
        *(short8*)&lA[seg * 512 + lane * 8] = p;
      } else {
        const bf16* ga = (const bf16*)Av + (size_t)(bm + row) * lda + kt + scol;
        gload16(ga, &lA[seg * 512]);
      }
      const bf16* gb = B + (size_t)(bn + row) * ldb + kt + scol;
      gload16(gb, &lB[seg * 512]);
    }
    __syncthreads();
#pragma unroll
    for (int ks = 0; ks < 2; ++ks) {
      short8 af[4], bfr[4];
      const int ko = ks * 32 + kg * 8;
#pragma unroll
      for (int mi = 0; mi < 4; ++mi)
        af[mi] = *(const short8*)&lA[(wm + mi * 16 + l15) * 64 + ko];
#pragma unroll
      for (int ni = 0; ni < 4; ++ni)
        bfr[ni] = *(const short8*)&lB[(wn + ni * 16 + l15) * 64 + ko];
#pragma unroll
      for (int mi = 0; mi < 4; ++mi)
#pragma unroll
        for (int ni = 0; ni < 4; ++ni)
          acc[mi][ni] = __builtin_amdgcn_mfma_f32_16x16x32_bf16(
              bfr[ni], af[mi], acc[mi][ni], 0, 0, 0);
    }
  }

  // Epilogue: D[row=n][col=m] -> lane holds m = wm+mi*16+l15, n = wn+ni*16+kg*4+r
#pragma unroll
  for (int mi = 0; mi < 4; ++mi) {
    const size_t mrow = (size_t)bm + wm + mi * 16 + l15;
#pragma unroll
    for (int ni = 0; ni < 4; ++ni) {
      const int nb = bn + wn + ni * 16 + kg * 4;
      f32x4 bv = *(const f32x4*)&bias[nb];
      f32x4 r = acc[mi][ni] + bv;
      if constexpr (OUT_BF16) {
        short4v o;
        o[0] = f2bf(r[0]); o[1] = f2bf(r[1]); o[2] = f2bf(r[2]); o[3] = f2bf(r[3]);
        *(short4v*)((bf16*)Cv + mrow * ldc + nb) = o;
      } else {
        *(f32x4*)((float*)Cv + mrow * ldc + nb) = r;
      }
    }
  }
}

// ---------------- block attention ----------------
// One block per (b,n) 16-row chunk; 4 waves x 2 heads. qkv[m][1536] bf16,
// q cols [0,512), k [512,1024), v [1024,1536). ctx written into q-region
// after a block barrier (all reads done first).
__global__ __launch_bounds__(256) void attn_kernel(bf16* __restrict__ qkv)
{
  const int tid  = threadIdx.x;
  const int wave = tid >> 6;
  const int lane = tid & 63;
  const int l15  = lane & 15;
  const int kg   = lane >> 4;
  const size_t mbase = (size_t)blockIdx.x * 16;  // (b*512+n)*16 == b*8192+n*16

  f32x4 ctxv[2][4];

#pragma unroll
  for (int hi = 0; hi < 2; ++hi) {
    const int h = wave + hi * 4;
    const bf16* qp = qkv + (mbase + l15) * 1536 + h * 64 + kg * 8;
    short8 qf0 = *(const short8*)qp;
    short8 qf1 = *(const short8*)(qp + 32);
    short8 kf0 = *(const short8*)(qp + 512);
    short8 kf1 = *(const short8*)(qp + 544);

    // scoresT[k][q] = K . Q^T  (swapped operands: softmax axis lane-local-ish)
    f32x4 st = (f32x4)0.f;
    st = __builtin_amdgcn_mfma_f32_16x16x32_bf16(kf0, qf0, st, 0, 0, 0);
    st = __builtin_amdgcn_mfma_f32_16x16x32_bf16(kf1, qf1, st, 0, 0, 0);

    float s[4];
#pragma unroll
    for (int r = 0; r < 4; ++r) s[r] = st[r] * 0.125f;  // 1/sqrt(64)
    float mx = fmaxf(fmaxf(s[0], s[1]), fmaxf(s[2], s[3]));
    mx = fmaxf(mx, __shfl_xor(mx, 16));
    mx = fmaxf(mx, __shfl_xor(mx, 32));
    float p[4], sum = 0.f;
#pragma unroll
    for (int r = 0; r < 4; ++r) { p[r] = __expf(s[r] - mx); sum += p[r]; }
    sum += __shfl_xor(sum, 16);
    sum += __shfl_xor(sum, 32);
    const float inv = 1.f / sum;

    // P fragment: lane holds P[q=l15][k=kg*4+r] -> exactly 16x16x16 A layout
    short4v pf;
#pragma unroll
    for (int r = 0; r < 4; ++r) pf[r] = f2bf(p[r] * inv);

    const bf16* vp = qkv + mbase * 1536 + 1024 + h * 64;
#pragma unroll
    for (int dt = 0; dt < 4; ++dt) {
      short4v vf;
#pragma unroll
      for (int jj = 0; jj < 4; ++jj)
        vf[jj] = *(const short*)(vp + (size_t)(kg * 4 + jj) * 1536 + dt * 16 + l15);
      f32x4 c = (f32x4)0.f;
      c = __builtin_amdgcn_mfma_f32_16x16x16bf16_1k(pf, vf, c, 0, 0, 0);
      ctxv[hi][dt] = c;  // lane holds ctx[q=kg*4+r][d = dt*16 + l15]
    }
  }

  __syncthreads();  // all reads of q-region complete before overwrite

#pragma unroll
  for (int hi = 0; hi < 2; ++hi) {
    const int h = wave + hi * 4;
#pragma unroll
    for (int dt = 0; dt < 4; ++dt) {
#pragma unroll
      for (int r = 0; r < 4; ++r) {
        ((short*)qkv)[(mbase + kg * 4 + r) * 1536 + h * 64 + dt * 16 + l15] =
            f2bf(ctxv[hi][dt][r]);
      }
    }
  }
}

// ---------------- launch ----------------
extern "C" void kernel_launch(void* const* d_in, const int* in_sizes, int n_in,
                              void* d_out, int out_size, void* d_ws, size_t ws_size,
                              hipStream_t stream) {
  (void)in_sizes; (void)n_in; (void)out_size; (void)ws_size;
  const float* x     = (const float*)d_in[0];
  const float* w_in  = (const float*)d_in[1];
  const float* b_in  = (const float*)d_in[2];
  const float* w_out = (const float*)d_in[3];
  const float* b_out = (const float*)d_in[4];
  float* out = (float*)d_out;

  char* ws = (char*)d_ws;
  bf16* qkv   = (bf16*)ws;                                   // 65536*1536 bf16
  bf16* winb  = (bf16*)(ws + (size_t)65536 * 1536 * 2);      // 1536*512
  bf16* woutb = (bf16*)(ws + (size_t)65536 * 1536 * 2 + (size_t)786432 * 2);

  cvt_f32_to_bf16<<<768, 256, 0, stream>>>(w_in, winb, 786432 / 4);
  cvt_f32_to_bf16<<<256, 256, 0, stream>>>(w_out, woutb, 262144 / 4);

  // QKV = x @ w_in^T + b_in   (M=65536, N=1536, K=512), bf16 out
  dim3 g1(12, 512);
  gemm_bt<true, true><<<g1, 256, 0, stream>>>(
      (const void*)x, 512, winb, 512, b_in, (void*)qkv, 1536, 512);

  // block attention, ctx -> q-region of qkv
  attn_kernel<<<4096, 256, 0, stream>>>(qkv);

  // out = ctx @ w_out^T + b_out  (M=65536, N=512, K=512), fp32 out
  dim3 g2(4, 512);
  gemm_bt<false, false><<<g2, 256, 0, stream>>>(
      (const void*)qkv, 1536, woutb, 512, b_out, (void*)out, 512, 512);
}

// Round 2
// 314.286 us; speedup vs baseline: 1.2473x; 1.2473x over previous
//
#include <hip/hip_runtime.h>
#include <hip/hip_bf16.h>

typedef __attribute__((ext_vector_type(4))) float f32x4;
typedef __attribute__((ext_vector_type(8))) short short8;
typedef __attribute__((ext_vector_type(4))) short short4v;
using bf16 = __hip_bfloat16;

__device__ __forceinline__ short f2bf(float x) {
  union { bf16 h; short s; } u;
  u.h = __float2bfloat16(x);
  return u.s;
}

__device__ __forceinline__ void gload16(const void* g, void* l) {
  __builtin_amdgcn_global_load_lds(
      (const __attribute__((address_space(1))) void*)g,
      (__attribute__((address_space(3))) void*)l, 16, 0, 0);
}

// ---------------- fp32 -> bf16 conversion (grid-stride) ----------------
__global__ void cvt_f32_to_bf16(const float* __restrict__ src,
                                bf16* __restrict__ dst, int n4) {
  int i = blockIdx.x * blockDim.x + threadIdx.x;
  const int stride = gridDim.x * blockDim.x;
  for (; i < n4; i += stride) {
    f32x4 v = ((const f32x4*)src)[i];
    short4v o;
    o[0] = f2bf(v[0]); o[1] = f2bf(v[1]); o[2] = f2bf(v[2]); o[3] = f2bf(v[3]);
    ((short4v*)dst)[i] = o;
  }
}

// ---------------- GEMM: C[M][N] = A[M][K] * B[N][K]^T + bias ----------------
// 128x128 tile, BK=64, 256 threads (4 waves, 2x2), mfma_f32_16x16x32_bf16.
// - 1-D grid with bijective XCD swizzle (nwg % 8 == 0 required).
// - LDS XOR swizzle: linear global_load_lds dest + inverse-swizzled global
//   source col + swizzled ds_read addr (both-sides-or-neither, rule #21).
// - MFMA operands swapped so lane holds 4 consecutive N-cols -> packed stores.
template<bool OUT_BF16>
__global__ __launch_bounds__(256) void gemm_bt(
    const bf16* __restrict__ A, int lda,
    const bf16* __restrict__ B, int ldb,
    const float* __restrict__ bias,
    void* __restrict__ Cv, int ldc, int K, int nbx)
{
  __shared__ __align__(16) bf16 lA[128 * 64];
  __shared__ __align__(16) bf16 lB[128 * 64];
  const int tid  = threadIdx.x;
  const int wave = tid >> 6;
  const int lane = tid & 63;

  // XCD-aware remap: hardware round-robins blockIdx across 8 XCDs; give each
  // XCD a contiguous chunk of work ids so same-panel column tiles share L2.
  const int nwg = gridDim.x;
  const int d   = blockIdx.x;
  const int w   = (d & 7) * (nwg >> 3) + (d >> 3);
  const int bm  = (w / nbx) * 128;
  const int bn  = (w % nbx) * 128;

  const int wm = (wave >> 1) * 64;
  const int wn = (wave & 1) * 64;
  const int l15 = lane & 15;
  const int kg  = lane >> 4;
  const int rx  = l15 & 7;           // read-side row swizzle key

  f32x4 acc[4][4];
#pragma unroll
  for (int i = 0; i < 4; ++i)
#pragma unroll
    for (int j = 0; j < 4; ++j)
      acc[i][j] = (f32x4)0.f;

  const int srow = lane >> 3;                       // 0..7 within seg
  const int scol = ((lane & 7) ^ (srow & 7)) * 8;   // inverse-swizzled src col

  for (int kt = 0; kt < K; kt += 64) {
    __syncthreads();
#pragma unroll
    for (int it = 0; it < 4; ++it) {
      const int seg = it * 4 + wave;     // 0..15, 8 rows each
      const int row = seg * 8 + srow;
      gload16(A + (size_t)(bm + row) * lda + kt + scol, &lA[seg * 512]);
      gload16(B + (size_t)(bn + row) * ldb + kt + scol, &lB[seg * 512]);
    }
    __syncthreads();
#pragma unroll
    for (int ks = 0; ks < 2; ++ks) {
      short8 af[4], bfr[4];
      const int slot = ks * 4 + kg;      // logical 16B k-slot 0..7
      const int po   = (slot ^ rx) * 8;  // swizzled ds_read col (elements)
#pragma unroll
      for (int mi = 0; mi < 4; ++mi)
        af[mi] = *(const short8*)&lA[(wm + mi * 16 + l15) * 64 + po];
#pragma unroll
      for (int ni = 0; ni < 4; ++ni)
        bfr[ni] = *(const short8*)&lB[(wn + ni * 16 + l15) * 64 + po];
#pragma unroll
      for (int mi = 0; mi < 4; ++mi)
#pragma unroll
        for (int ni = 0; ni < 4; ++ni)
          acc[mi][ni] = __builtin_amdgcn_mfma_f32_16x16x32_bf16(
              bfr[ni], af[mi], acc[mi][ni], 0, 0, 0);
    }
  }

  // Epilogue: lane holds m = wm+mi*16+l15, n = wn+ni*16+kg*4+r (4 consecutive n)
#pragma unroll
  for (int mi = 0; mi < 4; ++mi) {
    const size_t mrow = (size_t)bm + wm + mi * 16 + l15;
#pragma unroll
    for (int ni = 0; ni < 4; ++ni) {
      const int nb = bn + wn + ni * 16 + kg * 4;
      f32x4 bv = *(const f32x4*)&bias[nb];
      f32x4 r = acc[mi][ni] + bv;
      if constexpr (OUT_BF16) {
        short4v o;
        o[0] = f2bf(r[0]); o[1] = f2bf(r[1]); o[2] = f2bf(r[2]); o[3] = f2bf(r[3]);
        *(short4v*)((bf16*)Cv + mrow * ldc + nb) = o;
      } else {
        *(f32x4*)((float*)Cv + mrow * ldc + nb) = r;
      }
    }
  }
}

// ---------------- block attention ----------------
// One block per (b,n) 16-row chunk; 4 waves x 2 heads. qkv[m][1536] bf16,
// q cols [0,512), k [512,1024), v [1024,1536). ctx written into q-region
// after a block barrier (all reads done first).
__global__ __launch_bounds__(256) void attn_kernel(bf16* __restrict__ qkv)
{
  const int tid  = threadIdx.x;
  const int wave = tid >> 6;
  const int lane = tid & 63;
  const int l15  = lane & 15;
  const int kg   = lane >> 4;
  const size_t mbase = (size_t)blockIdx.x * 16;

  f32x4 ctxv[2][4];

#pragma unroll
  for (int hi = 0; hi < 2; ++hi) {
    const int h = wave + hi * 4;
    const bf16* qp = qkv + (mbase + l15) * 1536 + h * 64 + kg * 8;
    short8 qf0 = *(const short8*)qp;
    short8 qf1 = *(const short8*)(qp + 32);
    short8 kf0 = *(const short8*)(qp + 512);
    short8 kf1 = *(const short8*)(qp + 544);

    // scoresT[k][q] = K . Q^T (swapped operands)
    f32x4 st = (f32x4)0.f;
    st = __builtin_amdgcn_mfma_f32_16x16x32_bf16(kf0, qf0, st, 0, 0, 0);
    st = __builtin_amdgcn_mfma_f32_16x16x32_bf16(kf1, qf1, st, 0, 0, 0);

    float s[4];
#pragma unroll
    for (int r = 0; r < 4; ++r) s[r] = st[r] * 0.125f;  // 1/sqrt(64)
    float mx = fmaxf(fmaxf(s[0], s[1]), fmaxf(s[2], s[3]));
    mx = fmaxf(mx, __shfl_xor(mx, 16));
    mx = fmaxf(mx, __shfl_xor(mx, 32));
    float p[4], sum = 0.f;
#pragma unroll
    for (int r = 0; r < 4; ++r) { p[r] = __expf(s[r] - mx); sum += p[r]; }
    sum += __shfl_xor(sum, 16);
    sum += __shfl_xor(sum, 32);
    const float inv = 1.f / sum;

    // P fragment: lane holds P[q=l15][k=kg*4+r] -> 16x16x16 layout
    short4v pf;
#pragma unroll
    for (int r = 0; r < 4; ++r) pf[r] = f2bf(p[r] * inv);

    const bf16* vp = qkv + mbase * 1536 + 1024 + h * 64;
#pragma unroll
    for (int dt = 0; dt < 4; ++dt) {
      short4v vf;
#pragma unroll
      for (int jj = 0; jj < 4; ++jj)
        vf[jj] = *(const short*)(vp + (size_t)(kg * 4 + jj) * 1536 + dt * 16 + l15);
      f32x4 c = (f32x4)0.f;
      c = __builtin_amdgcn_mfma_f32_16x16x16bf16_1k(pf, vf, c, 0, 0, 0);
      ctxv[hi][dt] = c;  // ctx[q=kg*4+r][d=dt*16+l15]
    }
  }

  __syncthreads();  // all q-region reads complete before overwrite

#pragma unroll
  for (int hi = 0; hi < 2; ++hi) {
    const int h = wave + hi * 4;
#pragma unroll
    for (int dt = 0; dt < 4; ++dt) {
#pragma unroll
      for (int r = 0; r < 4; ++r) {
        ((short*)qkv)[(mbase + kg * 4 + r) * 1536 + h * 64 + dt * 16 + l15] =
            f2bf(ctxv[hi][dt][r]);
      }
    }
  }
}

// ---------------- launch ----------------
extern "C" void kernel_launch(void* const* d_in, const int* in_sizes, int n_in,
                              void* d_out, int out_size, void* d_ws, size_t ws_size,
                              hipStream_t stream) {
  (void)in_sizes; (void)n_in; (void)out_size; (void)ws_size;
  const float* x     = (const float*)d_in[0];
  const float* w_in  = (const float*)d_in[1];
  const float* b_in  = (const float*)d_in[2];
  const float* w_out = (const float*)d_in[3];
  const float* b_out = (const float*)d_in[4];
  float* out = (float*)d_out;

  char* ws = (char*)d_ws;
  bf16* qkv   = (bf16*)ws;                                   // 65536*1536 bf16 = 201 MB
  bf16* winb  = (bf16*)(ws + (size_t)65536 * 1536 * 2);      // 1536*512
  bf16* woutb = (bf16*)(ws + (size_t)65536 * 1536 * 2 + (size_t)786432 * 2);
  // x in bf16 lives in d_out (67 MB in a 134 MB buffer) — GEMM2 overwrites
  // d_out afterwards and never reads xb, so this is safe scratch.
  bf16* xb = (bf16*)d_out;

  cvt_f32_to_bf16<<<768, 256, 0, stream>>>(w_in, winb, 786432 / 4);
  cvt_f32_to_bf16<<<256, 256, 0, stream>>>(w_out, woutb, 262144 / 4);
  cvt_f32_to_bf16<<<4096, 256, 0, stream>>>(x, xb, (65536 * 512) / 4);

  // QKV = xb @ w_in^T + b_in  (M=65536, N=1536, K=512), bf16 out
  gemm_bt<true><<<6144, 256, 0, stream>>>(
      xb, 512, winb, 512, b_in, (void*)qkv, 1536, 512, 12);

  // block attention, ctx -> q-region of qkv
  attn_kernel<<<4096, 256, 0, stream>>>(qkv);

  // out = ctx @ w_out^T + b_out  (M=65536, N=512, K=512), fp32 out
  gemm_bt<false><<<2048, 256, 0, stream>>>(
      qkv, 1536, woutb, 512, b_out, (void*)out, 512, 512, 4);
}

// Round 4
// 288.289 us; speedup vs baseline: 1.3598x; 1.0902x over previous
//
#include <hip/hip_runtime.h>
#include <hip/hip_bf16.h>

typedef __attribute__((ext_vector_type(4))) float f32x4;
typedef __attribute__((ext_vector_type(8))) short short8;
typedef __attribute__((ext_vector_type(4))) short short4v;
using bf16 = __hip_bfloat16;

__device__ __forceinline__ short f2bf(float x) {
  union { bf16 h; short s; } u;
  u.h = __float2bfloat16(x);
  return u.s;
}

__device__ __forceinline__ void gload16(const void* g, void* l) {
  __builtin_amdgcn_global_load_lds(
      (const __attribute__((address_space(1))) void*)g,
      (__attribute__((address_space(3))) void*)l, 16, 0, 0);
}

// ---------------- fp32 -> bf16 conversion (grid-stride) ----------------
__global__ void cvt_f32_to_bf16(const float* __restrict__ src,
                                bf16* __restrict__ dst, int n4) {
  int i = blockIdx.x * blockDim.x + threadIdx.x;
  const int stride = gridDim.x * blockDim.x;
  for (; i < n4; i += stride) {
    f32x4 v = ((const f32x4*)src)[i];
    short4v o;
    o[0] = f2bf(v[0]); o[1] = f2bf(v[1]); o[2] = f2bf(v[2]); o[3] = f2bf(v[3]);
    ((short4v*)dst)[i] = o;
  }
}

// ------------- 256x256 GEMM, BK=32, 4-buffer rotating pipeline -------------
// C = A * B^T + bias. K fixed 512 = 16 K-tiles, fully unrolled. 512 threads =
// 8 waves (2M x 4N), per-wave output 128x64, acc[8][4]. LDS 128 KiB =
// 4 bufs x (A 256x32 + B 256x32) bf16.
//
// Race-free rotation: during tile t we stage tile t+3 into buf (t+3)&3 =
// (t-1)&3, whose last reads finished before the t-1 -> t boundary barrier.
// Boundary close: counted s_waitcnt vmcnt(8) (= 2 tiles in flight) + one
// s_barrier per tile. vmcnt ledger: prologue stages t0,t1,t2 (12 loads),
// V(8) -> t0 resident; end-of-t V(8) -> everything except the last 2 staged
// tiles resident -> tile t+1 ready. Tail: V(4) @t13, V(0) @t14.
//
// LDS swizzle (64B rows): LDS[row][slot] = global[row][slot ^ ((row>>1)&3)];
// read undoes it. Spreads ds_read_b128 over all 8 bank-granule classes
// (2-way aliasing = free). global_load_lds dest stays linear; the source
// column is pre-swizzled (both-sides-or-neither, rule #21).
template<bool OUT_BF16>
__global__ __launch_bounds__(512) void gemm_bt(
    const bf16* __restrict__ A, int lda,
    const bf16* __restrict__ B, int ldb,
    const float* __restrict__ bias,
    void* __restrict__ Cv, int ldc, int nbx)
{
  __shared__ __align__(16) bf16 lA[4][256 * 32];
  __shared__ __align__(16) bf16 lB[4][256 * 32];

  const int tid  = threadIdx.x;
  const int lane = tid & 63;
  const int w    = tid >> 6;   // wave 0..7
  const int wr   = w >> 2;     // M half: rows wr*128..+127
  const int wc   = w & 3;      // N quarter: rows wc*64..+63
  const int l15  = lane & 15;
  const int kg   = lane >> 4;                    // k-slot 0..3
  const int po   = (kg ^ ((l15 >> 1) & 3)) * 8;  // swizzled read col (elems)

  const int nwg = gridDim.x;
  const int dd  = blockIdx.x;
  const int wid = (dd & 7) * (nwg >> 3) + (dd >> 3);  // bijective XCD swizzle
  const size_t bm = (size_t)(wid / nbx) * 256;
  const size_t bn = (size_t)(wid % nbx) * 256;

  // Staging: round h covers rows h*128..+127; thread -> row h*128+w*16+(lane>>2),
  // 16B at source col-slot (lane&3)^((lane>>3)&3) [= logical^(row>>1)&3].
  // LDS dest is wave-uniform base + lane*16B (linear).
  const int srow = w * 16 + (lane >> 2);
  const int scol = ((lane & 3) ^ ((lane >> 3) & 3)) * 8;
  const int wofs = w * 512;

  const bf16* Ab = A + (bm + srow) * lda + scol;
  const bf16* Bb = B + (bn + srow) * ldb + scol;

  f32x4 acc[8][4];
#pragma unroll
  for (int i = 0; i < 8; ++i)
#pragma unroll
    for (int j = 0; j < 4; ++j) acc[i][j] = (f32x4)0.f;

  short8 af[8], bq[4];

#define SA(buf, h, kt) gload16(Ab + (size_t)((h) * 128) * lda + (kt), \
                               &lA[buf][(h) * 4096 + wofs])
#define SB(buf, h, kt) gload16(Bb + (size_t)((h) * 128) * ldb + (kt), \
                               &lB[buf][(h) * 4096 + wofs])

#define CLOSE_V(N) do { \
    __builtin_amdgcn_sched_barrier(0); \
    asm volatile("s_waitcnt vmcnt(" #N ")" ::: "memory"); \
    __builtin_amdgcn_sched_barrier(0); \
    __builtin_amdgcn_s_barrier(); \
    __builtin_amdgcn_sched_barrier(0); \
    asm volatile("" ::: "memory"); } while (0)

  // prologue: stage tiles 0,1,2 (4 loads each)
  SA(0, 0, 0);  SA(0, 1, 0);  SB(0, 0, 0);  SB(0, 1, 0);
  SA(1, 0, 32); SA(1, 1, 32); SB(1, 0, 32); SB(1, 1, 32);
  SA(2, 0, 64); SA(2, 1, 64); SB(2, 0, 64); SB(2, 1, 64);
  CLOSE_V(8);

#pragma unroll
  for (int t = 0; t < 16; ++t) {
    const int cur = t & 3, pf = (t + 3) & 3;
    const int kt3 = (t + 3) * 32;

    // fragment reads from the (stable) current buffer
#pragma unroll
    for (int mi = 0; mi < 8; ++mi)
      af[mi] = *(const short8*)&lA[cur][(wr * 128 + mi * 16 + l15) * 32 + po];
#pragma unroll
    for (int ni = 0; ni < 4; ++ni)
      bq[ni] = *(const short8*)&lB[cur][(wc * 64 + ni * 16 + l15) * 32 + po];

    // stage tile t+3 (writes buf last read in tile t-1, barrier-separated)
    if (t < 13) { SA(pf, 0, kt3); SB(pf, 0, kt3); }

    __builtin_amdgcn_s_setprio(1);
#pragma unroll
    for (int mi = 0; mi < 4; ++mi)
#pragma unroll
      for (int ni = 0; ni < 4; ++ni)
        acc[mi][ni] = __builtin_amdgcn_mfma_f32_16x16x32_bf16(
            bq[ni], af[mi], acc[mi][ni], 0, 0, 0);
    __builtin_amdgcn_s_setprio(0);

    if (t < 13) { SA(pf, 1, kt3); SB(pf, 1, kt3); }

    __builtin_amdgcn_s_setprio(1);
#pragma unroll
    for (int mi = 4; mi < 8; ++mi)
#pragma unroll
      for (int ni = 0; ni < 4; ++ni)
        acc[mi][ni] = __builtin_amdgcn_mfma_f32_16x16x32_bf16(
            bq[ni], af[mi], acc[mi][ni], 0, 0, 0);
    __builtin_amdgcn_s_setprio(0);

    if (t <= 12)      CLOSE_V(8);
    else if (t == 13) CLOSE_V(4);
    else if (t == 14) CLOSE_V(0);
    // t == 15: fall through to epilogue
  }

#undef SA
#undef SB
#undef CLOSE_V

  // Epilogue: lane holds m = bm+wr*128+mi*16+l15, n = bn+wc*64+ni*16+kg*4+j
#pragma unroll
  for (int mi = 0; mi < 8; ++mi) {
    const size_t mrow = bm + wr * 128 + mi * 16 + l15;
#pragma unroll
    for (int ni = 0; ni < 4; ++ni) {
      const int nb = (int)bn + wc * 64 + ni * 16 + kg * 4;
      f32x4 bv = *(const f32x4*)&bias[nb];
      f32x4 r = acc[mi][ni] + bv;
      if constexpr (OUT_BF16) {
        short4v o;
        o[0] = f2bf(r[0]); o[1] = f2bf(r[1]); o[2] = f2bf(r[2]); o[3] = f2bf(r[3]);
        *(short4v*)((bf16*)Cv + mrow * ldc + nb) = o;
      } else {
        *(f32x4*)((float*)Cv + mrow * ldc + nb) = r;
      }
    }
  }
}

// ---------------- block attention ----------------
// One block per (b,n) 16-row chunk; 4 waves x 2 heads. qkv[m][1536] bf16,
// q cols [0,512), k [512,1024), v [1024,1536). ctx written into q-region
// after a block barrier (all reads done first).
__global__ __launch_bounds__(256) void attn_kernel(bf16* __restrict__ qkv)
{
  const int tid  = threadIdx.x;
  const int wave = tid >> 6;
  const int lane = tid & 63;
  const int l15  = lane & 15;
  const int kg   = lane >> 4;
  const size_t mbase = (size_t)blockIdx.x * 16;

  f32x4 ctxv[2][4];

#pragma unroll
  for (int hi = 0; hi < 2; ++hi) {
    const int h = wave + hi * 4;
    const bf16* qp = qkv + (mbase + l15) * 1536 + h * 64 + kg * 8;
    short8 qf0 = *(const short8*)qp;
    short8 qf1 = *(const short8*)(qp + 32);
    short8 kf0 = *(const short8*)(qp + 512);
    short8 kf1 = *(const short8*)(qp + 544);

    // scoresT[k][q] = K . Q^T (swapped operands)
    f32x4 st = (f32x4)0.f;
    st = __builtin_amdgcn_mfma_f32_16x16x32_bf16(kf0, qf0, st, 0, 0, 0);
    st = __builtin_amdgcn_mfma_f32_16x16x32_bf16(kf1, qf1, st, 0, 0, 0);

    float s[4];
#pragma unroll
    for (int r = 0; r < 4; ++r) s[r] = st[r] * 0.125f;  // 1/sqrt(64)
    float mx = fmaxf(fmaxf(s[0], s[1]), fmaxf(s[2], s[3]));
    mx = fmaxf(mx, __shfl_xor(mx, 16));
    mx = fmaxf(mx, __shfl_xor(mx, 32));
    float p[4], sum = 0.f;
#pragma unroll
    for (int r = 0; r < 4; ++r) { p[r] = __expf(s[r] - mx); sum += p[r]; }
    sum += __shfl_xor(sum, 16);
    sum += __shfl_xor(sum, 32);
    const float inv = 1.f / sum;

    // P fragment: lane holds P[q=l15][k=kg*4+r] -> 16x16x16 layout
    short4v pf;
#pragma unroll
    for (int r = 0; r < 4; ++r) pf[r] = f2bf(p[r] * inv);

    const bf16* vp = qkv + mbase * 1536 + 1024 + h * 64;
#pragma unroll
    for (int dt = 0; dt < 4; ++dt) {
      short4v vf;
#pragma unroll
      for (int jj = 0; jj < 4; ++jj)
        vf[jj] = *(const short*)(vp + (size_t)(kg * 4 + jj) * 1536 + dt * 16 + l15);
      f32x4 c = (f32x4)0.f;
      c = __builtin_amdgcn_mfma_f32_16x16x16bf16_1k(pf, vf, c, 0, 0, 0);
      ctxv[hi][dt] = c;  // ctx[q=kg*4+r][d=dt*16+l15]
    }
  }

  __syncthreads();  // all q-region reads complete before overwrite

#pragma unroll
  for (int hi = 0; hi < 2; ++hi) {
    const int h = wave + hi * 4;
#pragma unroll
    for (int dt = 0; dt < 4; ++dt) {
#pragma unroll
      for (int r = 0; r < 4; ++r) {
        ((short*)qkv)[(mbase + kg * 4 + r) * 1536 + h * 64 + dt * 16 + l15] =
            f2bf(ctxv[hi][dt][r]);
      }
    }
  }
}

// ---------------- launch ----------------
extern "C" void kernel_launch(void* const* d_in, const int* in_sizes, int n_in,
                              void* d_out, int out_size, void* d_ws, size_t ws_size,
                              hipStream_t stream) {
  (void)in_sizes; (void)n_in; (void)out_size; (void)ws_size;
  const float* x     = (const float*)d_in[0];
  const float* w_in  = (const float*)d_in[1];
  const float* b_in  = (const float*)d_in[2];
  const float* w_out = (const float*)d_in[3];
  const float* b_out = (const float*)d_in[4];
  float* out = (float*)d_out;

  char* ws = (char*)d_ws;
  bf16* qkv   = (bf16*)ws;                                   // 65536*1536 bf16 = 201 MB
  bf16* winb  = (bf16*)(ws + (size_t)65536 * 1536 * 2);      // 1536*512
  bf16* woutb = (bf16*)(ws + (size_t)65536 * 1536 * 2 + (size_t)786432 * 2);
  // x in bf16 lives in d_out (67 MB in a 134 MB buffer) — GEMM2 overwrites
  // d_out afterwards and never reads xb, so this is safe scratch.
  bf16* xb = (bf16*)d_out;

  cvt_f32_to_bf16<<<768, 256, 0, stream>>>(w_in, winb, 786432 / 4);
  cvt_f32_to_bf16<<<256, 256, 0, stream>>>(w_out, woutb, 262144 / 4);
  cvt_f32_to_bf16<<<4096, 256, 0, stream>>>(x, xb, (65536 * 512) / 4);

  // QKV = xb @ w_in^T + b_in  (M=65536, N=1536, K=512), bf16 out
  gemm_bt<true><<<1536, 512, 0, stream>>>(
      xb, 512, winb, 512, b_in, (void*)qkv, 1536, 6);

  // block attention, ctx -> q-region of qkv
  attn_kernel<<<4096, 256, 0, stream>>>(qkv);

  // out = ctx @ w_out^T + b_out  (M=65536, N=512, K=512), fp32 out
  gemm_bt<false><<<512, 512, 0, stream>>>(
      qkv, 1536, woutb, 512, b_out, (void*)out, 512, 2);
}